// Round 8
// baseline (129.088 us; speedup 1.0000x reference)
//
#include <hip/hip_runtime.h>
#include <hip/hip_bf16.h>
#include <math.h>

#define Wd 8192
#define Bd 32

// ws layout (f32 offsets)
#define OFF_G    0                          // 3*64 (xseq fold vectors)
#define OFF_H    192                        // 3
#define OFF_BASE 195                        // 1
#define OFF_XSEQ 256                        // 32*8192
#define OFF_SXP  (OFF_XSEQ + Bd*Wd)         // 32*8*64 row-sum partials
#define OFF_RX   (OFF_SXP + Bd*8*64)        // 32*8*3*4096 lag-corr partials
#define OFF_T    (OFF_RX + Bd*8*12288)      // 32*3*1152 folded T entries
#define OFF_VEC  (OFF_T + Bd*3*1152)        // 32*5*128 (Xi, xi0, xi1, xim2, xim1)
#define OFF_WM   (OFF_VEC + Bd*640)         // 32*3 MTL scalars

typedef __attribute__((ext_vector_type(8))) short bf16x8;
typedef __attribute__((ext_vector_type(4))) float f32x4;

__device__ __forceinline__ unsigned short f2bf(float v) {
    return __builtin_bit_cast(unsigned short, __float2bfloat16(v));
}
__device__ __forceinline__ float bf2f(unsigned short h) {
    return __builtin_bit_cast(float, (unsigned)h << 16);
}

// ---------------- k0: fold sp through dwconv(V)+qkv -> G_j[64], H_j, base
__global__ __launch_bounds__(256) void k0_setup(const float* __restrict__ qkv_w,
                         const float* __restrict__ qkv_b,
                         const float* __restrict__ dw_w, const float* __restrict__ dw_b,
                         const float* __restrict__ sp_w, const float* __restrict__ sp_b,
                         float* __restrict__ ws)
{
    __shared__ float sw[64*64];
    __shared__ float sdw[192];
    __shared__ float ssp[64], sqb[64], sdb[64];
    int tid = threadIdx.x;
    for (int i = tid; i < 4096; i += 256) sw[i] = qkv_w[128*64 + i];
    if (tid < 192) { int c = tid/3, j = tid - 3*c; sdw[tid] = dw_w[(128+c)*9 + 3 + j]; }
    if (tid < 64)  { ssp[tid] = sp_w[tid]; sqb[tid] = qkv_b[128+tid]; sdb[tid] = dw_b[128+tid]; }
    __syncthreads();
    if (tid < 192) {
        int j = tid >> 6, ch = tid & 63;
        float acc = 0.f;
        #pragma unroll 8
        for (int c = 0; c < 64; c++)
            acc += ssp[c] * sdw[c*3+j] * sw[c*64 + ch];
        ws[OFF_G + j*64 + ch] = acc;
    } else if (tid < 195) {
        int j = tid - 192;
        float h = 0.f;
        #pragma unroll 8
        for (int c = 0; c < 64; c++)
            h += ssp[c] * sdw[c*3+j] * sqb[c];
        ws[OFF_H + j] = h;
    } else if (tid == 195) {
        float base = sp_b[0];
        #pragma unroll 8
        for (int c = 0; c < 64; c++) base += ssp[c] * sdb[c];
        ws[OFF_BASE] = base;
    }
}

// ---------------- kR: lag-correlations Rx_d (d=0,1,2) + row sums + xseq
// chunk = 1024 positions, 8 sub-tiles of 128. LDS x tile: [64 ch][152 bf16]
// window cols 0..143 <-> positions [p0-8, p0+136); owned = cols [8,136).
#define XSTR 152
#define XBYTES (64*XSTR*2)

__device__ __forceinline__ void loadpf(const float* __restrict__ xr, int wstart,
                                       int q, float4 pf[9]) {
    #pragma unroll
    for (int m = 0; m < 9; m++) {
        int gp = wstart - 8 + 36*q + 4*m;
        if (gp >= 0 && gp < Wd) pf[m] = *(const float4*)(xr + gp);
        else pf[m] = (float4){0.f,0.f,0.f,0.f};
    }
}
__device__ __forceinline__ float writepf(unsigned char* buf, int row, int q,
                                         const float4 pf[9]) {
    float ss = 0.f;
    #pragma unroll
    for (int m = 0; m < 9; m++) {
        int col0 = 36*q + 4*m;
        unsigned short h0 = f2bf(pf[m].x), h1 = f2bf(pf[m].y),
                       h2 = f2bf(pf[m].z), h3 = f2bf(pf[m].w);
        uint2 wv;
        wv.x = (unsigned)h0 | ((unsigned)h1 << 16);
        wv.y = (unsigned)h2 | ((unsigned)h3 << 16);
        *(uint2*)(buf + row*304 + col0*2) = wv;
        if (col0 >= 8 && col0 < 136)
            ss += (bf2f(h0) + bf2f(h1)) + (bf2f(h2) + bf2f(h3));
    }
    return ss;
}

__global__ __launch_bounds__(256) void kR(const float* __restrict__ x,
                                          float* __restrict__ ws)
{
    __shared__ __align__(16) unsigned char xb0[XBYTES];
    __shared__ __align__(16) unsigned char xb1[XBYTES];
    __shared__ float4 Gl[64];
    __shared__ float phib[3][132];
    __shared__ float sxb[64][4];

    const int tid = threadIdx.x, lane = tid & 63, wv = tid >> 6;
    const int g = lane >> 4, lr = lane & 15;
    const int chunk = blockIdx.x, b = blockIdx.y;
    const int w0 = chunk << 10;
    const int row = tid & 63, q = tid >> 6;
    const float* xr = x + ((size_t)b*64 + row)*Wd;

    if (tid < 64) Gl[tid] = (float4){ws[OFF_G+tid], ws[OFF_G+64+tid], ws[OFF_G+128+tid], 0.f};
    const float Hs0 = ws[OFF_H], Hs1 = ws[OFF_H+1], Hs2 = ws[OFF_H+2];
    const float base_ = ws[OFF_BASE];

    f32x4 a0[4], a1[4], a2[4];
    #pragma unroll
    for (int ct = 0; ct < 4; ct++) {
        a0[ct] = (f32x4){0,0,0,0}; a1[ct] = (f32x4){0,0,0,0}; a2[ct] = (f32x4){0,0,0,0};
    }
    float ssum = 0.f;
    float4 pf[9];

    loadpf(xr, w0, q, pf);
    ssum += writepf(xb0, row, q, pf);
    __syncthreads();

    for (int st = 0; st < 8; ++st) {
        const int p0 = w0 + (st << 7);
        unsigned char* bufc = (st & 1) ? xb1 : xb0;
        unsigned char* bufn = (st & 1) ? xb0 : xb1;

        if (st < 7) loadpf(xr, p0 + 128, q, pf);

        // ---- MFMA: Rx_d tiles; A = c-tile wv, B = c'-tile ct shifted by d
        #pragma unroll
        for (int k = 0; k < 4; k++) {
            const unsigned char* ap = bufc + (16*wv + lr)*304 + 16 + 64*k + 16*g;
            bf16x8 A = *(const bf16x8*)ap;
            #pragma unroll
            for (int ct = 0; ct < 4; ct++) {
                const unsigned char* bp = bufc + (16*ct + lr)*304 + 16 + 64*k + 16*g;
                uint4 u = *(const uint4*)bp;
                unsigned u4 = *(const unsigned*)(bp + 16);
                uint4 v1 = { (u.x>>16)|(u.y<<16), (u.y>>16)|(u.z<<16),
                             (u.z>>16)|(u.w<<16), (u.w>>16)|(u4<<16) };
                uint4 v2 = { u.y, u.z, u.w, u4 };
                a0[ct] = __builtin_amdgcn_mfma_f32_16x16x32_bf16(A, __builtin_bit_cast(bf16x8,u),  a0[ct],0,0,0);
                a1[ct] = __builtin_amdgcn_mfma_f32_16x16x32_bf16(A, __builtin_bit_cast(bf16x8,v1), a1[ct],0,0,0);
                a2[ct] = __builtin_amdgcn_mfma_f32_16x16x32_bf16(A, __builtin_bit_cast(bf16x8,v2), a2[ct],0,0,0);
            }
        }
        // ---- phi_j[t] = G_j . x[:, col 7+t]  (t -> position p0-1+t)
        if (tid < 130) {
            const unsigned short* xs = (const unsigned short*)bufc;
            float f0=0.f, f1=0.f, f2=0.f;
            int colw = 7 + tid;
            #pragma unroll 8
            for (int c = 0; c < 64; c++) {
                float xv = bf2f(xs[c*XSTR + colw]);
                float4 gv = Gl[c];
                f0 += gv.x*xv; f1 += gv.y*xv; f2 += gv.z*xv;
            }
            phib[0][tid]=f0; phib[1][tid]=f1; phib[2][tid]=f2;
        }
        __syncthreads();
        if (tid < 128) {
            int w = p0 + tid;
            float v = base_ + Hs0 + Hs1 + Hs2
                    + phib[0][tid] + phib[1][tid+1] + phib[2][tid+2];
            if (w == 0) v -= Hs0;
            if (w == Wd-1) v -= Hs2;
            ws[OFF_XSEQ + (size_t)b*Wd + w] = v;
        }
        if (st < 7) ssum += writepf(bufn, row, q, pf);
        __syncthreads();
    }

    // ---- write Rx partials: [d][c][c'], c = 16wv+4g+r, c' = 16ct+lr
    {
        float* pb = ws + OFF_RX + (size_t)(b*8 + chunk)*12288;
        #pragma unroll
        for (int ct = 0; ct < 4; ct++) {
            #pragma unroll
            for (int r = 0; r < 4; r++) {
                int c = 16*wv + 4*g + r, cc = 16*ct + lr;
                pb[         c*64 + cc] = a0[ct][r];
                pb[4096  +  c*64 + cc] = a1[ct][r];
                pb[8192  +  c*64 + cc] = a2[ct][r];
            }
        }
    }
    sxb[row][q] = ssum;
    __syncthreads();
    if (tid < 64)
        ws[OFF_SXP + (size_t)(b*8 + chunk)*64 + tid] =
            (sxb[tid][0] + sxb[tid][1]) + (sxb[tid][2] + sxb[tid][3]);
}

// ---------------- kF: bx<96: per-(b,lag) W-fold -> T entries (+vectors on d0)
//                      bx>=96: MTL branch scalars
#define KF_SW 0
#define KF_RX (128*68*4)
#define KF_NT (KF_RX + 64*68*4)
#define KF_SXR (KF_NT + 64*68*4)
#define KF_XC (KF_SXR + 64*4)
#define KF_BYTES (KF_XC + 256*4)

__device__ __forceinline__ float dot64p(const float* a, const float* b) {
    float s0=0.f,s1=0.f,s2=0.f,s3=0.f;
    #pragma unroll
    for (int k = 0; k < 64; k += 4) {
        float4 av = *(const float4*)(a+k), bv = *(const float4*)(b+k);
        s0 += av.x*bv.x; s1 += av.y*bv.y; s2 += av.z*bv.z; s3 += av.w*bv.w;
    }
    return (s0+s1)+(s2+s3);
}
__device__ __forceinline__ float blk_reduce_256(float v, float* sc) {
    #pragma unroll
    for (int off = 32; off > 0; off >>= 1) v += __shfl_down(v, off, 64);
    __syncthreads();
    if ((threadIdx.x & 63) == 0) sc[threadIdx.x >> 6] = v;
    __syncthreads();
    return sc[0] + sc[1] + sc[2] + sc[3];
}

__global__ __launch_bounds__(256) void kF(const float* __restrict__ x,
    const float* __restrict__ qkv_w,
    const float* __restrict__ up_w, const float* __restrict__ up_b,
    const float* __restrict__ c2_w, const float* __restrict__ c2_b,
    const float* __restrict__ ln2_w, const float* __restrict__ ln2_b,
    const float* __restrict__ c4_w, const float* __restrict__ c4_b,
    const float* __restrict__ ln4_w, const float* __restrict__ ln4_b,
    const float* __restrict__ c6_w, const float* __restrict__ c6_b,
    const float* __restrict__ ln6_w, const float* __restrict__ ln6_b,
    float* __restrict__ ws)
{
    __shared__ __align__(16) unsigned char sm[KF_BYTES];
    __shared__ float sc[4];
    const int tid = threadIdx.x, bx = blockIdx.x;

    if (bx < 96) {
        const int bb = bx / 3, d = bx - 3*bb;
        float* sW  = (float*)(sm + KF_SW);    // [128][68]
        float* sRx = (float*)(sm + KF_RX);    // [64][68]
        float* sNT = (float*)(sm + KF_NT);    // [64][68]
        float* sxr = (float*)(sm + KF_SXR);
        float* xcol = (float*)(sm + KF_XC);   // [4][64]

        #pragma unroll
        for (int k = 0; k < 8; k++) {
            int i4 = tid + 256*k;
            float4 v = ((const float4*)qkv_w)[i4];
            int r = i4 >> 4, c = (i4 & 15) << 2;
            *(float4*)(sW + r*68 + c) = v;
        }
        const float* rxp = ws + OFF_RX + (size_t)bb*8*12288 + d*4096;
        #pragma unroll
        for (int k = 0; k < 16; k++) {
            int idx = tid + 256*k;
            float s = 0.f;
            #pragma unroll
            for (int ch = 0; ch < 8; ch++) s += rxp[(size_t)ch*12288 + idx];
            sRx[(idx>>6)*68 + (idx&63)] = s;
        }
        if (d == 0) {
            if (tid < 64) {
                float s = 0.f;
                #pragma unroll
                for (int ch = 0; ch < 8; ch++) s += ws[OFF_SXP + (size_t)(bb*8+ch)*64 + tid];
                sxr[tid] = s;
            }
            {
                int c = tid & 63, v = tid >> 6;
                int colv = (v == 0) ? 0 : (v == 1) ? 1 : (v == 2) ? (Wd-2) : (Wd-1);
                xcol[v*64 + c] = x[((size_t)bb*64 + c)*Wd + colv];
            }
        }
        __syncthreads();
        if (d == 0 && tid < 128) {
            int r = tid;
            float Xi=0.f,x0=0.f,x1=0.f,xm2=0.f,xm1=0.f;
            #pragma unroll 8
            for (int c = 0; c < 64; c++) {
                float w = sW[r*68+c];
                Xi += w*sxr[c]; x0 += w*xcol[c]; x1 += w*xcol[64+c];
                xm2 += w*xcol[128+c]; xm1 += w*xcol[192+c];
            }
            float* vp = ws + OFF_VEC + bb*640;
            vp[r] = Xi; vp[128+r] = x0; vp[256+r] = x1; vp[384+r] = xm2; vp[512+r] = xm1;
        }
        // N1 = Rx_d @ Wk^T -> sNT[u][c]
        {
            int ro = tid >> 4, co = tid & 15;
            float acc[4][4] = {};
            for (int k = 0; k < 64; k += 4) {
                float4 av[4], bv[4];
                #pragma unroll
                for (int i = 0; i < 4; i++) av[i] = *(const float4*)(sRx + (4*ro+i)*68 + k);
                #pragma unroll
                for (int j = 0; j < 4; j++) bv[j] = *(const float4*)(sW + (64+4*co+j)*68 + k);
                #pragma unroll
                for (int i = 0; i < 4; i++)
                    #pragma unroll
                    for (int j = 0; j < 4; j++)
                        acc[i][j] += av[i].x*bv[j].x + av[i].y*bv[j].y
                                   + av[i].z*bv[j].z + av[i].w*bv[j].w;
            }
            __syncthreads();
            #pragma unroll
            for (int i = 0; i < 4; i++)
                #pragma unroll
                for (int j = 0; j < 4; j++)
                    sNT[(4*co+j)*68 + 4*ro+i] = acc[i][j];
        }
        __syncthreads();
        float* Tp = ws + OFF_T + (size_t)(bb*3 + d)*1152;
        for (int e = tid; e < 512; e += 256) {
            int t = e >> 3, u = ((e>>6)<<3) + (e&7);
            Tp[e] = dot64p(sW + t*68, sNT + u*68);          // T_d[q_t, k_u]
        }
        if (tid < 64) Tp[1088 + tid] = dot64p(sW + (64+tid)*68, sNT + tid*68);  // diag_k
        __syncthreads();
        // N0 = Rx_d @ Wq^T -> overwrite sNT[t][c]
        {
            int ro = tid >> 4, co = tid & 15;
            float acc[4][4] = {};
            for (int k = 0; k < 64; k += 4) {
                float4 av[4], bv[4];
                #pragma unroll
                for (int i = 0; i < 4; i++) av[i] = *(const float4*)(sRx + (4*ro+i)*68 + k);
                #pragma unroll
                for (int j = 0; j < 4; j++) bv[j] = *(const float4*)(sW + (4*co+j)*68 + k);
                #pragma unroll
                for (int i = 0; i < 4; i++)
                    #pragma unroll
                    for (int j = 0; j < 4; j++)
                        acc[i][j] += av[i].x*bv[j].x + av[i].y*bv[j].y
                                   + av[i].z*bv[j].z + av[i].w*bv[j].w;
            }
            __syncthreads();
            #pragma unroll
            for (int i = 0; i < 4; i++)
                #pragma unroll
                for (int j = 0; j < 4; j++)
                    sNT[(4*co+j)*68 + 4*ro+i] = acc[i][j];
        }
        __syncthreads();
        for (int e = tid; e < 512; e += 256) {
            int t = e >> 3, u = ((e>>6)<<3) + (e&7);
            Tp[512 + e] = dot64p(sW + (64+u)*68, sNT + t*68); // T_d[k_u, q_t]
        }
        if (tid < 64) Tp[1024 + tid] = dot64p(sW + tid*68, sNT + tid*68);       // diag_q
        return;
    }

    // ---- MTL role
    int t2 = bx - 96;
    int br = t2 >> 5, b = t2 & 31;
    float* ys = (float*)sm;
    const float *cw, *lw, *lb; float cb; int K, lo;
    if (br == 0)      { cw = c2_w; cb = c2_b[0]; lw = ln2_w; lb = ln2_b; K = 2; lo = 0; }
    else if (br == 1) { cw = c4_w; cb = c4_b[0]; lw = ln4_w; lb = ln4_b; K = 4; lo = 1; }
    else              { cw = c6_w; cb = c6_b[0]; lw = ln6_w; lb = ln6_b; K = 6; lo = 2; }
    float uw = up_w[br], ub = up_b[br];
    const float* xr = ws + OFF_XSEQ + (size_t)b*Wd;

    float s = 0.f, s2 = 0.f;
    for (int w = tid; w < Wd; w += 256) {
        float y = cb;
        for (int m = 0; m < K; m++) {
            int p = w + m - lo;
            if (p >= 0 && p < Wd) y += cw[m] * (uw*xr[p] + ub);
        }
        ys[w] = y; s += y; s2 += y*y;
    }
    float mu = blk_reduce_256(s, sc) * (1.f/Wd);
    __syncthreads();
    float Ey2 = blk_reduce_256(s2, sc) * (1.f/Wd);
    float var = fmaxf(Ey2 - mu*mu, 0.f);
    float inv = 1.f / sqrtf(var + 1e-5f);
    float se = 0.f;
    for (int w = tid; w < Wd; w += 256) {
        float tt = (ys[w]-mu)*inv*lw[w] + lb[w];
        se += (tt > 0.f) ? tt : expm1f(tt);
    }
    float m = blk_reduce_256(se, sc) * (1.f/Wd);
    if (tid == 0) ws[OFF_WM + b*3 + br] = m;
}

// ---------------- k5: assemble S from T + edges -> softmax -> E/F -> stream
__global__ __launch_bounds__(256) void k5_out(const float* __restrict__ ws,
    const float* __restrict__ qkv_b, const float* __restrict__ dw_w,
    const float* __restrict__ dw_b, const float* __restrict__ temperature,
    const float* __restrict__ mp_w, const float* __restrict__ mp_b,
    const float* __restrict__ up_w, const float* __restrict__ up_b,
    const float* __restrict__ proj_w, const float* __restrict__ proj_b,
    float* __restrict__ out)
{
    __shared__ float sT3[3][1152];
    __shared__ float vec[5][128];
    __shared__ float qb_[128], tb_[128], tp_[128][3];
    __shared__ float Sq[512], dgq[64], dgk[64];
    __shared__ float snk[64], sal[64], sbe[64], sE[64], sF[64];
    __shared__ float red[64][8];
    const int tid = threadIdx.x;
    const int chunk = blockIdx.x, b = blockIdx.y;

    for (int i = tid; i < 3456; i += 256) ((float*)sT3)[i] = ws[OFF_T + (size_t)b*3456 + i];
    for (int i = tid; i < 640; i += 256) ((float*)vec)[i] = ws[OFF_VEC + b*640 + i];
    if (tid < 128) {
        qb_[tid] = qkv_b[tid]; tb_[tid] = dw_b[tid];
        tp_[tid][0] = dw_w[tid*9+3]; tp_[tid][1] = dw_w[tid*9+4]; tp_[tid][2] = dw_w[tid*9+5];
    }
    __syncthreads();

    for (int ee = tid; ee < 640; ee += 256) {
        int r, s; float Tpv[3], Tmv[3];
        if (ee < 512) {
            r = ee >> 3; s = 64 + ((ee>>6)<<3) + (ee&7);
            #pragma unroll
            for (int d = 0; d < 3; d++) { Tpv[d] = sT3[d][ee]; Tmv[d] = sT3[d][512+ee]; }
        } else if (ee < 576) {
            r = s = ee - 512;
            #pragma unroll
            for (int d = 0; d < 3; d++) { Tpv[d] = Tmv[d] = sT3[d][1024 + r]; }
        } else {
            int u = ee - 576; r = s = 64 + u;
            #pragma unroll
            for (int d = 0; d < 3; d++) { Tpv[d] = Tmv[d] = sT3[d][1088 + u]; }
        }
        float Xr = vec[0][r], Xs = vec[0][s];
        float x0r = vec[1][r], x0s = vec[1][s];
        float x1r = vec[2][r], x1s = vec[2][s];
        float xm2r = vec[3][r], xm2s = vec[3][s];
        float xm1r = vec[4][r], xm1s = vec[4][s];
        float qr = qb_[r], qs = qb_[s];
        float C5[5];
        #pragma unroll
        for (int dd = 0; dd < 3; dd++) {
            float head_s = (dd>=1 ? x0s : 0.f) + (dd>=2 ? x1s : 0.f);
            float tail_r = (dd>=1 ? xm1r : 0.f) + (dd>=2 ? xm2r : 0.f);
            C5[2+dd] = Tpv[dd] + qr*(Xs - head_s) + qs*(Xr - tail_r) + (8192.f - dd)*qr*qs;
            float head_r = (dd>=1 ? x0r : 0.f) + (dd>=2 ? x1r : 0.f);
            float tail_s = (dd>=1 ? xm1s : 0.f) + (dd>=2 ? xm2s : 0.f);
            C5[2-dd] = Tmv[dd] + qs*(Xr - head_r) + qr*(Xs - tail_s) + (8192.f - dd)*qr*qs;
        }
        float y0r = x0r + qr, y0s = x0s + qs;
        float ym1r = xm1r + qr, ym1s = xm1s + qs;
        float Yr = Xr + 8192.f*qr, Ys = Xs + 8192.f*qs;
        float tbr = tb_[r], tbs = tb_[s];
        float G = 8192.f * tbr * tbs;
        float sumr = 0.f, sums = 0.f;
        #pragma unroll
        for (int i = 0; i < 3; i++) {
            sumr += tp_[r][i] * (Yr - (i==0 ? ym1r : 0.f) - (i==2 ? y0r : 0.f));
            sums += tp_[s][i] * (Ys - (i==0 ? ym1s : 0.f) - (i==2 ? y0s : 0.f));
        }
        G += tbr * sums + tbs * sumr;
        #pragma unroll
        for (int i = 0; i < 3; i++)
            #pragma unroll
            for (int j = 0; j < 3; j++) {
                float P = C5[2 + j - i];
                if (i == 2 && j == 2) P -= y0r * y0s;
                if (i == 0 && j == 0) P -= ym1r * ym1s;
                G += tp_[r][i] * tp_[s][j] * P;
            }
        if (ee < 512) Sq[ee] = G;
        else if (ee < 576) dgq[ee-512] = G;
        else dgk[ee-576] = G;
    }
    __syncthreads();

    float nq = 0.f;
    if (tid < 64) {
        nq = fmaxf(sqrtf(fmaxf(dgq[tid], 0.f)), 1e-12f);
        snk[tid] = fmaxf(sqrtf(fmaxf(dgk[tid], 0.f)), 1e-12f);
    }
    __syncthreads();
    if (tid < 64) {
        int h = tid >> 3;
        float temp = temperature[h];
        float lg[8], mx = -1e30f;
        #pragma unroll
        for (int d = 0; d < 8; d++) {
            lg[d] = Sq[tid*8 + d] / (nq * snk[h*8 + d]) * temp;
            mx = fmaxf(mx, lg[d]);
        }
        float sum = 0.f;
        #pragma unroll
        for (int d = 0; d < 8; d++) { lg[d] = expf(lg[d] - mx); sum += lg[d]; }
        float a = 0.f, bb2 = 0.f;
        #pragma unroll
        for (int d = 0; d < 8; d++) {
            float at = lg[d] / sum;
            a   += at * mp_w[h*8 + d];
            bb2 += at * mp_b[h*8 + d];
        }
        sal[tid] = a; sbe[tid] = bb2;
    }
    __syncthreads();
    {
        float m2 = ws[OFF_WM + b*3], m4 = ws[OFF_WM + b*3 + 1], m6 = ws[OFF_WM + b*3 + 2];
        float A_ = m2*up_w[0] + m4*up_w[1] + m6*up_w[2];
        float C_ = m2*up_b[0] + m4*up_b[1] + m6*up_b[2];
        int o = tid & 63, q = tid >> 6;
        float pa = 0.f, pb2 = 0.f;
        #pragma unroll
        for (int k = 0; k < 16; k++) {
            int c = 16*q + k;
            float pw = proj_w[o*64 + c];
            pa += pw * sal[c]; pb2 += pw * sbe[c];
        }
        red[o][q] = pa; red[o][4+q] = pb2;
        __syncthreads();
        if (tid < 64) {
            float Pa = (red[tid][0]+red[tid][1]) + (red[tid][2]+red[tid][3]);
            float Pb = (red[tid][4]+red[tid][5]) + (red[tid][6]+red[tid][7]);
            sE[tid] = A_ * Pa;
            sF[tid] = C_ * Pa + Pb + proj_b[tid];
        }
    }
    __syncthreads();
    const float4* xs4 = (const float4*)(ws + OFF_XSEQ + (size_t)b*Wd);
    float4 xv = xs4[chunk*128 + (tid & 127)];
    int oh = tid >> 7;
    float4* ob = (float4*)out + (size_t)b*64*2048 + chunk*128 + (tid & 127);
    #pragma unroll 8
    for (int oo = 0; oo < 32; oo++) {
        int o = oh*32 + oo;
        float e = sE[o], f = sF[o];
        float4 rr = { e*xv.x + f, e*xv.y + f, e*xv.z + f, e*xv.w + f };
        ob[(size_t)o*2048] = rr;
    }
}

extern "C" void kernel_launch(void* const* d_in, const int* in_sizes, int n_in,
                              void* d_out, int out_size, void* d_ws, size_t ws_size,
                              hipStream_t stream) {
    const float* x      = (const float*)d_in[0];
    const float* qkv_w  = (const float*)d_in[1];
    const float* qkv_b  = (const float*)d_in[2];
    const float* dw_w   = (const float*)d_in[3];
    const float* dw_b   = (const float*)d_in[4];
    const float* proj_w = (const float*)d_in[5];
    const float* proj_b = (const float*)d_in[6];
    const float* temperature = (const float*)d_in[7];
    const float* sp_w   = (const float*)d_in[8];
    const float* sp_b   = (const float*)d_in[9];
    const float* up_w   = (const float*)d_in[10];
    const float* up_b   = (const float*)d_in[11];
    const float* c2_w   = (const float*)d_in[12];
    const float* c2_b   = (const float*)d_in[13];
    const float* ln2_w  = (const float*)d_in[14];
    const float* ln2_b  = (const float*)d_in[15];
    const float* c4_w   = (const float*)d_in[16];
    const float* c4_b   = (const float*)d_in[17];
    const float* ln4_w  = (const float*)d_in[18];
    const float* ln4_b  = (const float*)d_in[19];
    const float* c6_w   = (const float*)d_in[20];
    const float* c6_b   = (const float*)d_in[21];
    const float* ln6_w  = (const float*)d_in[22];
    const float* ln6_b  = (const float*)d_in[23];
    const float* mp_w   = (const float*)d_in[24];
    const float* mp_b   = (const float*)d_in[25];
    float* ws  = (float*)d_ws;
    float* out = (float*)d_out;

    k0_setup<<<1, 256, 0, stream>>>(qkv_w, qkv_b, dw_w, dw_b, sp_w, sp_b, ws);
    kR<<<dim3(8, 32), 256, 0, stream>>>(x, ws);
    kF<<<192, 256, 0, stream>>>(x, qkv_w, up_w, up_b,
        c2_w, c2_b, ln2_w, ln2_b, c4_w, c4_b, ln4_w, ln4_b, c6_w, c6_b, ln6_w, ln6_b,
        ws);
    k5_out<<<dim3(16, 32), 256, 0, stream>>>(ws, qkv_b, dw_w, dw_b, temperature,
        mp_w, mp_b, up_w, up_b, proj_w, proj_b, out);
}

// Round 9
// 121.422 us; speedup vs baseline: 1.0631x; 1.0631x over previous
//
#include <hip/hip_runtime.h>
#include <hip/hip_bf16.h>
#include <math.h>

#define Wd 8192
#define Bd 32
#define NCH 16          // chunk groups per batch (512 positions each)

// ws layout (f32 offsets)
#define OFF_G    0                          // 3*64
#define OFF_H    192                        // 3
#define OFF_BASE 195                        // 1
#define OFF_XSEQ 256                        // 32*8192
#define OFF_SXP  (OFF_XSEQ + Bd*Wd)         // Bd*NCH*64 row-sum partials
#define OFF_RX   (OFF_SXP + Bd*NCH*64)      // Bd*NCH*3*4096 lag-corr partials
#define OFF_T    (OFF_RX + Bd*NCH*12288)    // 32*3*1152 folded T entries
#define OFF_VEC  (OFF_T + Bd*3*1152)        // 32*5*128
#define OFF_WM   (OFF_VEC + Bd*640)         // 32*3

typedef __attribute__((ext_vector_type(8))) short bf16x8;
typedef __attribute__((ext_vector_type(4))) float f32x4;

__device__ __forceinline__ unsigned short f2bf(float v) {
    return __builtin_bit_cast(unsigned short, __float2bfloat16(v));
}
__device__ __forceinline__ float bf2f(unsigned short h) {
    return __builtin_bit_cast(float, (unsigned)h << 16);
}

// ---------------- k0: fold sp through dwconv(V)+qkv -> G_j[64], H_j, base
__global__ __launch_bounds__(256) void k0_setup(const float* __restrict__ qkv_w,
                         const float* __restrict__ qkv_b,
                         const float* __restrict__ dw_w, const float* __restrict__ dw_b,
                         const float* __restrict__ sp_w, const float* __restrict__ sp_b,
                         float* __restrict__ ws)
{
    __shared__ float sw[64*64];
    __shared__ float sdw[192];
    __shared__ float ssp[64], sqb[64], sdb[64];
    int tid = threadIdx.x;
    for (int i = tid; i < 4096; i += 256) sw[i] = qkv_w[128*64 + i];
    if (tid < 192) { int c = tid/3, j = tid - 3*c; sdw[tid] = dw_w[(128+c)*9 + 3 + j]; }
    if (tid < 64)  { ssp[tid] = sp_w[tid]; sqb[tid] = qkv_b[128+tid]; sdb[tid] = dw_b[128+tid]; }
    __syncthreads();
    if (tid < 192) {
        int j = tid >> 6, ch = tid & 63;
        float acc = 0.f;
        #pragma unroll 8
        for (int c = 0; c < 64; c++)
            acc += ssp[c] * sdw[c*3+j] * sw[c*64 + ch];
        ws[OFF_G + j*64 + ch] = acc;
    } else if (tid < 195) {
        int j = tid - 192;
        float h = 0.f;
        #pragma unroll 8
        for (int c = 0; c < 64; c++)
            h += ssp[c] * sdw[c*3+j] * sqb[c];
        ws[OFF_H + j] = h;
    } else if (tid == 195) {
        float base = sp_b[0];
        #pragma unroll 8
        for (int c = 0; c < 64; c++) base += ssp[c] * sdb[c];
        ws[OFF_BASE] = base;
    }
}

// ---------------- kR: lag-correlations Rx_d + row sums + xseq
// 512 positions/block as 2 sub-tiles of 256. LDS x tile [64 ch][272+pad pos] bf16,
// 16B-granule XOR swizzle. Window cols 0..271 <-> positions [p0-8, p0+264).
#define ROWB 576

__device__ __forceinline__ int swzoff(int row, int gr) {
    int s = (gr < 32) ? (gr ^ (row & 7)) : gr;
    return row*ROWB + s*16;
}

__device__ __forceinline__ void loadsub(const float* __restrict__ xbase, int p0,
                                        float4 pf[17]) {
    #pragma unroll
    for (int m = 0; m < 17; m++) {
        int F = threadIdx.x + 256*m;
        int row = F / 68, c4 = F - 68*row;
        int p = p0 - 8 + 4*c4;
        const float* src = xbase + (size_t)row*Wd + p;
        if ((unsigned)p <= (unsigned)(Wd-4)) {
            pf[m] = *(const float4*)src;
        } else {
            float4 v;
            v.x = ((unsigned)(p  ) < (unsigned)Wd) ? src[0] : 0.f;
            v.y = ((unsigned)(p+1) < (unsigned)Wd) ? src[1] : 0.f;
            v.z = ((unsigned)(p+2) < (unsigned)Wd) ? src[2] : 0.f;
            v.w = ((unsigned)(p+3) < (unsigned)Wd) ? src[3] : 0.f;
            pf[m] = v;
        }
    }
}
__device__ __forceinline__ void writesub(unsigned char* xb, const float4 pf[17]) {
    #pragma unroll
    for (int m = 0; m < 17; m++) {
        int F = threadIdx.x + 256*m;
        int row = F / 68, c4 = F - 68*row;
        uint2 wv;
        wv.x = (unsigned)f2bf(pf[m].x) | ((unsigned)f2bf(pf[m].y) << 16);
        wv.y = (unsigned)f2bf(pf[m].z) | ((unsigned)f2bf(pf[m].w) << 16);
        *(uint2*)(xb + swzoff(row, c4 >> 1) + (c4 & 1)*8) = wv;
    }
}

__global__ __launch_bounds__(256) void kR(const float* __restrict__ x,
                                          float* __restrict__ ws)
{
    __shared__ __align__(16) unsigned char xb[64*ROWB];
    __shared__ float phib[3][260];
    __shared__ float4 Gl[64];
    __shared__ float sxb[64][4];

    const int tid = threadIdx.x, lane = tid & 63, wv = tid >> 6;
    const int g = lane >> 4, lr = lane & 15;
    const int grp = blockIdx.x, b = blockIdx.y;
    const float* xbase = x + (size_t)b*64*Wd;

    if (tid < 64) Gl[tid] = (float4){ws[OFF_G+tid], ws[OFF_G+64+tid], ws[OFF_G+128+tid], 0.f};
    const float Hs0 = ws[OFF_H], Hs1 = ws[OFF_H+1], Hs2 = ws[OFF_H+2];
    const float base_ = ws[OFF_BASE];

    f32x4 a0[4], a1[4], a2[4];
    #pragma unroll
    for (int ct = 0; ct < 4; ct++) {
        a0[ct] = (f32x4){0,0,0,0}; a1[ct] = (f32x4){0,0,0,0}; a2[ct] = (f32x4){0,0,0,0};
    }
    float rs = 0.f;
    float4 pf[17];

    loadsub(xbase, grp*512, pf);
    writesub(xb, pf);
    __syncthreads();

    #pragma unroll
    for (int s = 0; s < 2; s++) {
        const int p0 = grp*512 + s*256;
        if (s == 0) loadsub(xbase, p0 + 256, pf);   // T14: issue early, write late

        // ---- MFMA: Rx_d tiles; A = c-tile wv, B = c'-tile ct shifted by d
        #pragma unroll
        for (int ks = 0; ks < 8; ks++) {
            int gr0 = 1 + 4*ks + g;
            bf16x8 A = *(const bf16x8*)(xb + swzoff(16*wv + lr, gr0));
            #pragma unroll
            for (int ct = 0; ct < 4; ct++) {
                int rb = 16*ct + lr;
                uint4 u = *(const uint4*)(xb + swzoff(rb, gr0));
                unsigned u4 = *(const unsigned*)(xb + swzoff(rb, gr0 + 1));
                uint4 v1 = { (u.x>>16)|(u.y<<16), (u.y>>16)|(u.z<<16),
                             (u.z>>16)|(u.w<<16), (u.w>>16)|(u4<<16) };
                uint4 v2 = { u.y, u.z, u.w, u4 };
                a0[ct] = __builtin_amdgcn_mfma_f32_16x16x32_bf16(A, __builtin_bit_cast(bf16x8,u),  a0[ct],0,0,0);
                a1[ct] = __builtin_amdgcn_mfma_f32_16x16x32_bf16(A, __builtin_bit_cast(bf16x8,v1), a1[ct],0,0,0);
                a2[ct] = __builtin_amdgcn_mfma_f32_16x16x32_bf16(A, __builtin_bit_cast(bf16x8,v2), a2[ct],0,0,0);
            }
        }
        // ---- phi_j[t] = G_j . x[:, col 7+t]   (col 7 <-> position p0-1)
        for (int ci = tid; ci < 258; ci += 256) {
            int col = 7 + ci;
            int grc = col >> 3, off = (col & 7)*2;
            float f0 = 0.f, f1 = 0.f, f2 = 0.f;
            #pragma unroll 8
            for (int c = 0; c < 64; c++) {
                float xv = bf2f(*(const unsigned short*)(xb + swzoff(c, grc) + off));
                float4 gv = Gl[c];
                f0 += gv.x*xv; f1 += gv.y*xv; f2 += gv.z*xv;
            }
            phib[0][ci] = f0; phib[1][ci] = f1; phib[2][ci] = f2;
        }
        // ---- row sums over owned cols 8..263 (granules 1..32)
        {
            int row = tid & 63, q = tid >> 6;
            float ssum = 0.f;
            #pragma unroll
            for (int i = 0; i < 8; i++) {
                uint4 u = *(const uint4*)(xb + swzoff(row, 1 + 8*q + i));
                ssum += (bf2f((unsigned short)u.x) + bf2f((unsigned short)(u.x>>16)))
                      + (bf2f((unsigned short)u.y) + bf2f((unsigned short)(u.y>>16)))
                      + (bf2f((unsigned short)u.z) + bf2f((unsigned short)(u.z>>16)))
                      + (bf2f((unsigned short)u.w) + bf2f((unsigned short)(u.w>>16)));
            }
            rs += ssum;
        }
        __syncthreads();    // phib ready
        {
            int w = p0 + tid;
            float v = base_ + Hs0 + Hs1 + Hs2
                    + phib[0][tid] + phib[1][tid+1] + phib[2][tid+2];
            if (w == 0) v -= Hs0;
            if (w == Wd-1) v -= Hs2;
            ws[OFF_XSEQ + (size_t)b*Wd + w] = v;
        }
        __syncthreads();    // all xb/phib reads done
        if (s == 0) {
            writesub(xb, pf);
            __syncthreads();
        }
    }

    // ---- write Rx partials: [d][c][c'], c = 16wv+4g+r, c' = 16ct+lr
    {
        float* pb = ws + OFF_RX + (size_t)(b*NCH + grp)*12288;
        #pragma unroll
        for (int ct = 0; ct < 4; ct++) {
            #pragma unroll
            for (int r = 0; r < 4; r++) {
                int c = 16*wv + 4*g + r, cc = 16*ct + lr;
                pb[        c*64 + cc] = a0[ct][r];
                pb[4096 +  c*64 + cc] = a1[ct][r];
                pb[8192 +  c*64 + cc] = a2[ct][r];
            }
        }
    }
    {
        int row = tid & 63, q = tid >> 6;
        sxb[row][q] = rs;
    }
    __syncthreads();
    if (tid < 64)
        ws[OFF_SXP + (size_t)(b*NCH + grp)*64 + tid] =
            (sxb[tid][0] + sxb[tid][1]) + (sxb[tid][2] + sxb[tid][3]);
}

// ---------------- kF: bx<96: per-(b,lag) W-fold -> T entries (+vectors on d0)
//                      bx>=96: MTL branch scalars
#define KF_SW 0
#define KF_RX (128*68*4)
#define KF_NT (KF_RX + 64*68*4)
#define KF_SXR (KF_NT + 64*68*4)
#define KF_XC (KF_SXR + 64*4)
#define KF_BYTES (KF_XC + 256*4)

__device__ __forceinline__ float dot64p(const float* a, const float* b) {
    float s0=0.f,s1=0.f,s2=0.f,s3=0.f;
    #pragma unroll
    for (int k = 0; k < 64; k += 4) {
        float4 av = *(const float4*)(a+k), bv = *(const float4*)(b+k);
        s0 += av.x*bv.x; s1 += av.y*bv.y; s2 += av.z*bv.z; s3 += av.w*bv.w;
    }
    return (s0+s1)+(s2+s3);
}
__device__ __forceinline__ float blk_reduce_256(float v, float* sc) {
    #pragma unroll
    for (int off = 32; off > 0; off >>= 1) v += __shfl_down(v, off, 64);
    __syncthreads();
    if ((threadIdx.x & 63) == 0) sc[threadIdx.x >> 6] = v;
    __syncthreads();
    return sc[0] + sc[1] + sc[2] + sc[3];
}

__global__ __launch_bounds__(256) void kF(const float* __restrict__ x,
    const float* __restrict__ qkv_w,
    const float* __restrict__ up_w, const float* __restrict__ up_b,
    const float* __restrict__ c2_w, const float* __restrict__ c2_b,
    const float* __restrict__ ln2_w, const float* __restrict__ ln2_b,
    const float* __restrict__ c4_w, const float* __restrict__ c4_b,
    const float* __restrict__ ln4_w, const float* __restrict__ ln4_b,
    const float* __restrict__ c6_w, const float* __restrict__ c6_b,
    const float* __restrict__ ln6_w, const float* __restrict__ ln6_b,
    float* __restrict__ ws)
{
    __shared__ __align__(16) unsigned char sm[KF_BYTES];
    __shared__ float sc[4];
    const int tid = threadIdx.x, bx = blockIdx.x;

    if (bx < 96) {
        const int bb = bx / 3, d = bx - 3*bb;
        float* sW  = (float*)(sm + KF_SW);    // [128][68]
        float* sRx = (float*)(sm + KF_RX);    // [64][68]
        float* sNT = (float*)(sm + KF_NT);    // [64][68]
        float* sxr = (float*)(sm + KF_SXR);
        float* xcol = (float*)(sm + KF_XC);   // [4][64]

        #pragma unroll
        for (int k = 0; k < 8; k++) {
            int i4 = tid + 256*k;
            float4 v = ((const float4*)qkv_w)[i4];
            int r = i4 >> 4, c = (i4 & 15) << 2;
            *(float4*)(sW + r*68 + c) = v;
        }
        const float* rxp = ws + OFF_RX + (size_t)bb*NCH*12288 + d*4096;
        #pragma unroll
        for (int k = 0; k < 16; k++) {
            int idx = tid + 256*k;
            float s = 0.f;
            #pragma unroll
            for (int ch = 0; ch < NCH; ch++) s += rxp[(size_t)ch*12288 + idx];
            sRx[(idx>>6)*68 + (idx&63)] = s;
        }
        if (d == 0) {
            if (tid < 64) {
                float s = 0.f;
                #pragma unroll
                for (int ch = 0; ch < NCH; ch++) s += ws[OFF_SXP + (size_t)(bb*NCH+ch)*64 + tid];
                sxr[tid] = s;
            }
            {
                int c = tid & 63, v = tid >> 6;
                int colv = (v == 0) ? 0 : (v == 1) ? 1 : (v == 2) ? (Wd-2) : (Wd-1);
                xcol[v*64 + c] = x[((size_t)bb*64 + c)*Wd + colv];
            }
        }
        __syncthreads();
        if (d == 0 && tid < 128) {
            int r = tid;
            float Xi=0.f,x0=0.f,x1=0.f,xm2=0.f,xm1=0.f;
            #pragma unroll 8
            for (int c = 0; c < 64; c++) {
                float w = sW[r*68+c];
                Xi += w*sxr[c]; x0 += w*xcol[c]; x1 += w*xcol[64+c];
                xm2 += w*xcol[128+c]; xm1 += w*xcol[192+c];
            }
            float* vp = ws + OFF_VEC + bb*640;
            vp[r] = Xi; vp[128+r] = x0; vp[256+r] = x1; vp[384+r] = xm2; vp[512+r] = xm1;
        }
        // N1 = Rx_d @ Wk^T -> sNT[u][c]
        {
            int ro = tid >> 4, co = tid & 15;
            float acc[4][4] = {};
            for (int k = 0; k < 64; k += 4) {
                float4 av[4], bv[4];
                #pragma unroll
                for (int i = 0; i < 4; i++) av[i] = *(const float4*)(sRx + (4*ro+i)*68 + k);
                #pragma unroll
                for (int j = 0; j < 4; j++) bv[j] = *(const float4*)(sW + (64+4*co+j)*68 + k);
                #pragma unroll
                for (int i = 0; i < 4; i++)
                    #pragma unroll
                    for (int j = 0; j < 4; j++)
                        acc[i][j] += av[i].x*bv[j].x + av[i].y*bv[j].y
                                   + av[i].z*bv[j].z + av[i].w*bv[j].w;
            }
            __syncthreads();
            #pragma unroll
            for (int i = 0; i < 4; i++)
                #pragma unroll
                for (int j = 0; j < 4; j++)
                    sNT[(4*co+j)*68 + 4*ro+i] = acc[i][j];
        }
        __syncthreads();
        float* Tp = ws + OFF_T + (size_t)(bb*3 + d)*1152;
        for (int e = tid; e < 512; e += 256) {
            int t = e >> 3, u = ((e>>6)<<3) + (e&7);
            Tp[e] = dot64p(sW + t*68, sNT + u*68);          // T_d[q_t, k_u]
        }
        if (tid < 64) Tp[1088 + tid] = dot64p(sW + (64+tid)*68, sNT + tid*68);  // diag_k
        __syncthreads();
        // N0 = Rx_d @ Wq^T -> overwrite sNT[t][c]
        {
            int ro = tid >> 4, co = tid & 15;
            float acc[4][4] = {};
            for (int k = 0; k < 64; k += 4) {
                float4 av[4], bv[4];
                #pragma unroll
                for (int i = 0; i < 4; i++) av[i] = *(const float4*)(sRx + (4*ro+i)*68 + k);
                #pragma unroll
                for (int j = 0; j < 4; j++) bv[j] = *(const float4*)(sW + (4*co+j)*68 + k);
                #pragma unroll
                for (int i = 0; i < 4; i++)
                    #pragma unroll
                    for (int j = 0; j < 4; j++)
                        acc[i][j] += av[i].x*bv[j].x + av[i].y*bv[j].y
                                   + av[i].z*bv[j].z + av[i].w*bv[j].w;
            }
            __syncthreads();
            #pragma unroll
            for (int i = 0; i < 4; i++)
                #pragma unroll
                for (int j = 0; j < 4; j++)
                    sNT[(4*co+j)*68 + 4*ro+i] = acc[i][j];
        }
        __syncthreads();
        for (int e = tid; e < 512; e += 256) {
            int t = e >> 3, u = ((e>>6)<<3) + (e&7);
            Tp[512 + e] = dot64p(sW + (64+u)*68, sNT + t*68); // T_d[k_u, q_t]
        }
        if (tid < 64) Tp[1024 + tid] = dot64p(sW + tid*68, sNT + tid*68);       // diag_q
        return;
    }

    // ---- MTL role
    int t2 = bx - 96;
    int br = t2 >> 5, b = t2 & 31;
    float* ys = (float*)sm;
    const float *cw, *lw, *lb; float cb; int K, lo;
    if (br == 0)      { cw = c2_w; cb = c2_b[0]; lw = ln2_w; lb = ln2_b; K = 2; lo = 0; }
    else if (br == 1) { cw = c4_w; cb = c4_b[0]; lw = ln4_w; lb = ln4_b; K = 4; lo = 1; }
    else              { cw = c6_w; cb = c6_b[0]; lw = ln6_w; lb = ln6_b; K = 6; lo = 2; }
    float uw = up_w[br], ub = up_b[br];
    const float* xr = ws + OFF_XSEQ + (size_t)b*Wd;

    float s = 0.f, s2 = 0.f;
    for (int w = tid; w < Wd; w += 256) {
        float y = cb;
        for (int m = 0; m < K; m++) {
            int p = w + m - lo;
            if (p >= 0 && p < Wd) y += cw[m] * (uw*xr[p] + ub);
        }
        ys[w] = y; s += y; s2 += y*y;
    }
    float mu = blk_reduce_256(s, sc) * (1.f/Wd);
    __syncthreads();
    float Ey2 = blk_reduce_256(s2, sc) * (1.f/Wd);
    float var = fmaxf(Ey2 - mu*mu, 0.f);
    float inv = 1.f / sqrtf(var + 1e-5f);
    float se = 0.f;
    for (int w = tid; w < Wd; w += 256) {
        float tt = (ys[w]-mu)*inv*lw[w] + lb[w];
        se += (tt > 0.f) ? tt : expm1f(tt);
    }
    float m = blk_reduce_256(se, sc) * (1.f/Wd);
    if (tid == 0) ws[OFF_WM + b*3 + br] = m;
}

// ---------------- k5: assemble S from T + edges -> softmax -> E/F -> stream
__global__ __launch_bounds__(256) void k5_out(const float* __restrict__ ws,
    const float* __restrict__ qkv_b, const float* __restrict__ dw_w,
    const float* __restrict__ dw_b, const float* __restrict__ temperature,
    const float* __restrict__ mp_w, const float* __restrict__ mp_b,
    const float* __restrict__ up_w, const float* __restrict__ up_b,
    const float* __restrict__ proj_w, const float* __restrict__ proj_b,
    float* __restrict__ out)
{
    __shared__ float sT3[3][1152];
    __shared__ float vec[5][128];
    __shared__ float qb_[128], tb_[128], tp_[128][3];
    __shared__ float Sq[512], dgq[64], dgk[64];
    __shared__ float snk[64], sal[64], sbe[64], sE[64], sF[64];
    __shared__ float red[64][8];
    const int tid = threadIdx.x;
    const int chunk = blockIdx.x, b = blockIdx.y;

    for (int i = tid; i < 3456; i += 256) ((float*)sT3)[i] = ws[OFF_T + (size_t)b*3456 + i];
    for (int i = tid; i < 640; i += 256) ((float*)vec)[i] = ws[OFF_VEC + b*640 + i];
    if (tid < 128) {
        qb_[tid] = qkv_b[tid]; tb_[tid] = dw_b[tid];
        tp_[tid][0] = dw_w[tid*9+3]; tp_[tid][1] = dw_w[tid*9+4]; tp_[tid][2] = dw_w[tid*9+5];
    }
    __syncthreads();

    for (int ee = tid; ee < 640; ee += 256) {
        int r, s; float Tpv[3], Tmv[3];
        if (ee < 512) {
            r = ee >> 3; s = 64 + ((ee>>6)<<3) + (ee&7);
            #pragma unroll
            for (int d = 0; d < 3; d++) { Tpv[d] = sT3[d][ee]; Tmv[d] = sT3[d][512+ee]; }
        } else if (ee < 576) {
            r = s = ee - 512;
            #pragma unroll
            for (int d = 0; d < 3; d++) { Tpv[d] = Tmv[d] = sT3[d][1024 + r]; }
        } else {
            int u = ee - 576; r = s = 64 + u;
            #pragma unroll
            for (int d = 0; d < 3; d++) { Tpv[d] = Tmv[d] = sT3[d][1088 + u]; }
        }
        float Xr = vec[0][r], Xs = vec[0][s];
        float x0r = vec[1][r], x0s = vec[1][s];
        float x1r = vec[2][r], x1s = vec[2][s];
        float xm2r = vec[3][r], xm2s = vec[3][s];
        float xm1r = vec[4][r], xm1s = vec[4][s];
        float qr = qb_[r], qs = qb_[s];
        float C5[5];
        #pragma unroll
        for (int dd = 0; dd < 3; dd++) {
            float head_s = (dd>=1 ? x0s : 0.f) + (dd>=2 ? x1s : 0.f);
            float tail_r = (dd>=1 ? xm1r : 0.f) + (dd>=2 ? xm2r : 0.f);
            C5[2+dd] = Tpv[dd] + qr*(Xs - head_s) + qs*(Xr - tail_r) + (8192.f - dd)*qr*qs;
            float head_r = (dd>=1 ? x0r : 0.f) + (dd>=2 ? x1r : 0.f);
            float tail_s = (dd>=1 ? xm1s : 0.f) + (dd>=2 ? xm2s : 0.f);
            C5[2-dd] = Tmv[dd] + qs*(Xr - head_r) + qr*(Xs - tail_s) + (8192.f - dd)*qr*qs;
        }
        float y0r = x0r + qr, y0s = x0s + qs;
        float ym1r = xm1r + qr, ym1s = xm1s + qs;
        float Yr = Xr + 8192.f*qr, Ys = Xs + 8192.f*qs;
        float tbr = tb_[r], tbs = tb_[s];
        float G = 8192.f * tbr * tbs;
        float sumr = 0.f, sums = 0.f;
        #pragma unroll
        for (int i = 0; i < 3; i++) {
            sumr += tp_[r][i] * (Yr - (i==0 ? ym1r : 0.f) - (i==2 ? y0r : 0.f));
            sums += tp_[s][i] * (Ys - (i==0 ? ym1s : 0.f) - (i==2 ? y0s : 0.f));
        }
        G += tbr * sums + tbs * sumr;
        #pragma unroll
        for (int i = 0; i < 3; i++)
            #pragma unroll
            for (int j = 0; j < 3; j++) {
                float P = C5[2 + j - i];
                if (i == 2 && j == 2) P -= y0r * y0s;
                if (i == 0 && j == 0) P -= ym1r * ym1s;
                G += tp_[r][i] * tp_[s][j] * P;
            }
        if (ee < 512) Sq[ee] = G;
        else if (ee < 576) dgq[ee-512] = G;
        else dgk[ee-576] = G;
    }
    __syncthreads();

    float nq = 0.f;
    if (tid < 64) {
        nq = fmaxf(sqrtf(fmaxf(dgq[tid], 0.f)), 1e-12f);
        snk[tid] = fmaxf(sqrtf(fmaxf(dgk[tid], 0.f)), 1e-12f);
    }
    __syncthreads();
    if (tid < 64) {
        int h = tid >> 3;
        float temp = temperature[h];
        float lg[8], mx = -1e30f;
        #pragma unroll
        for (int d = 0; d < 8; d++) {
            lg[d] = Sq[tid*8 + d] / (nq * snk[h*8 + d]) * temp;
            mx = fmaxf(mx, lg[d]);
        }
        float sum = 0.f;
        #pragma unroll
        for (int d = 0; d < 8; d++) { lg[d] = expf(lg[d] - mx); sum += lg[d]; }
        float a = 0.f, bb2 = 0.f;
        #pragma unroll
        for (int d = 0; d < 8; d++) {
            float at = lg[d] / sum;
            a   += at * mp_w[h*8 + d];
            bb2 += at * mp_b[h*8 + d];
        }
        sal[tid] = a; sbe[tid] = bb2;
    }
    __syncthreads();
    {
        float m2 = ws[OFF_WM + b*3], m4 = ws[OFF_WM + b*3 + 1], m6 = ws[OFF_WM + b*3 + 2];
        float A_ = m2*up_w[0] + m4*up_w[1] + m6*up_w[2];
        float C_ = m2*up_b[0] + m4*up_b[1] + m6*up_b[2];
        int o = tid & 63, q = tid >> 6;
        float pa = 0.f, pb2 = 0.f;
        #pragma unroll
        for (int k = 0; k < 16; k++) {
            int c = 16*q + k;
            float pw = proj_w[o*64 + c];
            pa += pw * sal[c]; pb2 += pw * sbe[c];
        }
        red[o][q] = pa; red[o][4+q] = pb2;
        __syncthreads();
        if (tid < 64) {
            float Pa = (red[tid][0]+red[tid][1]) + (red[tid][2]+red[tid][3]);
            float Pb = (red[tid][4]+red[tid][5]) + (red[tid][6]+red[tid][7]);
            sE[tid] = A_ * Pa;
            sF[tid] = C_ * Pa + Pb + proj_b[tid];
        }
    }
    __syncthreads();
    const float4* xs4 = (const float4*)(ws + OFF_XSEQ + (size_t)b*Wd);
    float4 xv = xs4[chunk*128 + (tid & 127)];
    int oh = tid >> 7;
    float4* ob = (float4*)out + (size_t)b*64*2048 + chunk*128 + (tid & 127);
    #pragma unroll 8
    for (int oo = 0; oo < 32; oo++) {
        int o = oh*32 + oo;
        float e = sE[o], f = sF[o];
        float4 rr = { e*xv.x + f, e*xv.y + f, e*xv.z + f, e*xv.w + f };
        ob[(size_t)o*2048] = rr;
    }
}

extern "C" void kernel_launch(void* const* d_in, const int* in_sizes, int n_in,
                              void* d_out, int out_size, void* d_ws, size_t ws_size,
                              hipStream_t stream) {
    const float* x      = (const float*)d_in[0];
    const float* qkv_w  = (const float*)d_in[1];
    const float* qkv_b  = (const float*)d_in[2];
    const float* dw_w   = (const float*)d_in[3];
    const float* dw_b   = (const float*)d_in[4];
    const float* proj_w = (const float*)d_in[5];
    const float* proj_b = (const float*)d_in[6];
    const float* temperature = (const float*)d_in[7];
    const float* sp_w   = (const float*)d_in[8];
    const float* sp_b   = (const float*)d_in[9];
    const float* up_w   = (const float*)d_in[10];
    const float* up_b   = (const float*)d_in[11];
    const float* c2_w   = (const float*)d_in[12];
    const float* c2_b   = (const float*)d_in[13];
    const float* ln2_w  = (const float*)d_in[14];
    const float* ln2_b  = (const float*)d_in[15];
    const float* c4_w   = (const float*)d_in[16];
    const float* c4_b   = (const float*)d_in[17];
    const float* ln4_w  = (const float*)d_in[18];
    const float* ln4_b  = (const float*)d_in[19];
    const float* c6_w   = (const float*)d_in[20];
    const float* c6_b   = (const float*)d_in[21];
    const float* ln6_w  = (const float*)d_in[22];
    const float* ln6_b  = (const float*)d_in[23];
    const float* mp_w   = (const float*)d_in[24];
    const float* mp_b   = (const float*)d_in[25];
    float* ws  = (float*)d_ws;
    float* out = (float*)d_out;

    k0_setup<<<1, 256, 0, stream>>>(qkv_w, qkv_b, dw_w, dw_b, sp_w, sp_b, ws);
    kR<<<dim3(NCH, 32), 256, 0, stream>>>(x, ws);
    kF<<<192, 256, 0, stream>>>(x, qkv_w, up_w, up_b,
        c2_w, c2_b, ln2_w, ln2_b, c4_w, c4_b, ln4_w, ln4_b, c6_w, c6_b, ln6_w, ln6_b,
        ws);
    k5_out<<<dim3(16, 32), 256, 0, stream>>>(ws, qkv_b, dw_w, dw_b, temperature,
        mp_w, mp_b, up_w, up_b, proj_w, proj_b, out);
}